// Round 15
// baseline (1666.888 us; speedup 1.0000x reference)
//
#include <hip/hip_runtime.h>

typedef unsigned int uint;
typedef unsigned long long u64;
typedef unsigned short ushort;
typedef _Float16 f16;
typedef _Float16 f16x2 __attribute__((ext_vector_type(2)));
typedef _Float16 f16x8 __attribute__((ext_vector_type(8)));
typedef float f32x4 __attribute__((ext_vector_type(4)));

#define N_TYPES 10000
#define HID 256
#define G4 1024
#define BATCH 32
#define SEQ 1024

// ---------------- K1: path table: path[n][h] = sum_d cumw_d * emb[anc[n,d]][h]
__global__ void k_path(const int* __restrict__ anc, const float* __restrict__ weight,
                       const float* __restrict__ emb, int D, f16* __restrict__ path) {
  int n = blockIdx.x;
  int h = threadIdx.x;
  float acc = 0.f, cw = 1.f;
  for (int d = 0; d < D; ++d) {
    int a = anc[n * D + d];
    if (a < 0) break;
    acc += cw * emb[a * HID + h];
    cw *= weight[a];
  }
  path[n * HID + h] = (f16)acc;
}

// ---------------- K0: convert W_ih -> f16, W_hh -> transposed packed f16 pairs, bias = b_ih+b_hh
// whh_t layout: [128 kpair][1024 row] u32 (pair = f16 k, k+1 of row)
__global__ void k_conv(const float* __restrict__ wih, const float* __restrict__ whh,
                       const float* __restrict__ bih, const float* __restrict__ bhh,
                       f16* __restrict__ wih_h, uint* __restrict__ whh_t,
                       float* __restrict__ bias) {
  int i = blockIdx.x * 256 + threadIdx.x;   // 262144 threads
  wih_h[i] = (f16)wih[i];
  if (i < G4 * 128) {
    int row = i >> 7, p = i & 127;
    f16x2 v;
    v.x = (f16)whh[row * HID + 2 * p];
    v.y = (f16)whh[row * HID + 2 * p + 1];
    whh_t[p * G4 + row] = __builtin_bit_cast(uint, v);
  }
  if (i < G4) bias[i] = bih[i] + bhh[i];
}

// ---------------- K2: proj[n][dim][gate] = path[n]@W_ih^T + b (gate-packed epilogue)
#define BM 128
#define BN 128
#define BK 64
#define LPAD 72
__global__ __launch_bounds__(256) void k_gemm(const f16* __restrict__ A,
                                              const f16* __restrict__ Bw,
                                              const float* __restrict__ bias,
                                              f16* __restrict__ C) {
  __shared__ f16 sA[BM][LPAD];
  __shared__ f16 sB[BN][LPAD];
  int m0 = blockIdx.x * BM, n0 = blockIdx.y * BN;
  int tid = threadIdx.x;
  int wid = tid >> 6, lane = tid & 63;
  int wm = wid & 1, wn = wid >> 1;
  f32x4 acc[4][4] = {};
  for (int k0 = 0; k0 < 256; k0 += BK) {
    __syncthreads();
    int r = tid >> 3, kc = (tid & 7) * 8;
    for (int i = 0; i < 4; ++i) {
      int row = r + 32 * i;
      int gm = m0 + row;
      uint4 va = make_uint4(0u, 0u, 0u, 0u);
      if (gm < N_TYPES) va = *(const uint4*)&A[gm * 256 + k0 + kc];
      *(uint4*)&sA[row][kc] = va;
      uint4 vb = *(const uint4*)&Bw[(n0 + row) * 256 + k0 + kc];
      *(uint4*)&sB[row][kc] = vb;
    }
    __syncthreads();
#pragma unroll
    for (int ks = 0; ks < 2; ++ks) {
      f16x8 af[4], bf[4];
      int kk = ks * 32 + (lane >> 4) * 8;
#pragma unroll
      for (int mt = 0; mt < 4; ++mt)
        af[mt] = *(const f16x8*)&sA[wm * 64 + mt * 16 + (lane & 15)][kk];
#pragma unroll
      for (int nt = 0; nt < 4; ++nt)
        bf[nt] = *(const f16x8*)&sB[wn * 64 + nt * 16 + (lane & 15)][kk];
#pragma unroll
      for (int mt = 0; mt < 4; ++mt)
#pragma unroll
        for (int nt = 0; nt < 4; ++nt)
          acc[mt][nt] = __builtin_amdgcn_mfma_f32_16x16x32_f16(af[mt], bf[nt], acc[mt][nt], 0, 0, 0);
    }
  }
#pragma unroll
  for (int mt = 0; mt < 4; ++mt)
#pragma unroll
    for (int nt = 0; nt < 4; ++nt)
#pragma unroll
      for (int qq = 0; qq < 4; ++qq) {
        int row = m0 + wm * 64 + mt * 16 + (lane >> 4) * 4 + qq;
        int col = n0 + wn * 64 + nt * 16 + (lane & 15);
        int dim = col & 255, g = col >> 8;
        if (row < N_TYPES)
          C[row * G4 + dim * 4 + g] = (f16)(acc[mt][nt][qq] + bias[col]);
      }
}

// ---------------- K3: LSTM recurrence, v15 = R14 + VMEM-FREE PUBLISHER WAVE.
// Base (R5/R14, 1593/1597us): 256 WGs x 512 thr, bid=q*32+b; WG q owns dims
// [q*32,+32) x 4 gates = 128 rows, k-split over wave-pairs (kq=v>>1); per-thread
// w[32]; tagged {f16x2,step} u64 agent-relaxed fabric; single barrier/step;
// parity-double-buffered pl[2][4][128]; gate-packed proj.
//
// R14 post-mortem: the publisher wave (finale lanes) was also a POLLING wave --
// its next-step vmem poll waits the publish/out store acks (per-wave vmcnt),
// making it the per-step straggler. Fix: waves 6,7 share kq=3. Wave 6 polls the
// kq=3 words (it already did) and relays payloads -> LDS + release-flag (=step).
// Wave 7 (now the finale/publisher wave) issues ZERO vmem polls: it spins on the
// LDS flag (lgkmcnt-only, ~40cy cadence, immune to store acks), matvecs from
// uniform LDS broadcast reads, then finale/publish/out/x-prefetch. Its store acks
// retire during the next step's LDS spin without blocking anything.
__device__ __forceinline__ float dot2(uint wp, uint hp, float acc) {
#if __has_builtin(__builtin_amdgcn_fdot2)
  return __builtin_amdgcn_fdot2(__builtin_bit_cast(f16x2, wp),
                                __builtin_bit_cast(f16x2, hp), acc, false);
#else
  f16x2 a = __builtin_bit_cast(f16x2, wp);
  f16x2 b = __builtin_bit_cast(f16x2, hp);
  return acc + (float)a.x * (float)b.x + (float)a.y * (float)b.y;
#endif
}

__device__ __forceinline__ float sigm(float v) { return 1.f / (1.f + __expf(-v)); }
__device__ __forceinline__ float tanh_(float v) { return 1.f - 2.f / (__expf(2.f * v) + 1.f); }
__device__ __forceinline__ float f16u(ushort u) { return (float)__builtin_bit_cast(f16, u); }

__global__ __launch_bounds__(512, 2)
void k_lstm(const int* __restrict__ evs,
            const f16* __restrict__ proj,
            const uint* __restrict__ whh_t,
            u64* hglob,                 // [32 batch][2 slot][128 pair] tagged words
            float* __restrict__ out) {
  int bid = blockIdx.x;
  int b = bid & 31, q = bid >> 5;      // 8 WGs of batch b share bid%8 -> same XCD
  int t = threadIdx.x;
  int v = t >> 6, l = t & 63;
  int kq = v >> 1;                     // k-quarter, wave-uniform
  int rid = (v & 1) * 64 + l;          // local gate-row 0..127
  int rowg = (rid >> 5) * 256 + q * 32 + (rid & 31);   // global gate-row

  __shared__ float pl[2][4][128];      // partials [parity][kq][rid]
  __shared__ uint hrelay[2][32];       // wave6 -> wave7 kq=3 payload relay
  __shared__ uint hflag[2];            // relay flags (tag = step)

  if (t == 0) { hflag[0] = 0; hflag[1] = 0; }

  uint w[32];
#pragma unroll
  for (int i = 0; i < 32; ++i) w[i] = whh_t[(kq * 32 + i) * G4 + rowg];

  u64* hb = hglob + b * 256;           // [2][128]
  const int* ev = evs + b * SEQ;

  // finale wave = wave 7, lanes 0..31: carries x (gate-packed) one step ahead
  float x0 = 0.f, x1 = 0.f, x2 = 0.f, x3 = 0.f;
  if (v == 7 && l < 32) {
    ushort4 xv = *(const ushort4*)(proj + (long)ev[0] * G4 + (q * 32 + l) * 4);
    x0 = f16u(xv.x); x1 = f16u(xv.y); x2 = f16u(xv.z); x3 = f16u(xv.w);
  }

  __syncthreads();                     // hflag init visible

  float c = 0.f;

  for (int step = 0; step < SEQ; ++step) {
    int par = (step - 1) & 1;
    float a0 = 0.f, a1 = 0.f, a2 = 0.f, a3 = 0.f;

    if (v < 7) {
      // (1a) waves 0..6: vmem poll (lanes 32..63; these lanes never store)
      int h0 = 0;
      if (step > 0 && l >= 32) {
        const u64* src = hb + par * 128 + kq * 32 + (l - 32);
        u64 val;
        do {
          val = __hip_atomic_load(src, __ATOMIC_RELAXED, __HIP_MEMORY_SCOPE_AGENT);
        } while ((uint)(val >> 32) != (uint)step);
        h0 = (int)(uint)val;
      }
      // wave 6 relays kq=3 payloads to wave 7 before its own matvec
      if (v == 6 && step > 0) {
        if (l >= 32) hrelay[par][l - 32] = (uint)h0;
        if (l == 32)
          __hip_atomic_store(&hflag[par], (uint)step,
                             __ATOMIC_RELEASE, __HIP_MEMORY_SCOPE_WORKGROUP);
      }
      // (2a) matvec via readlane broadcast from lanes 32..63
#pragma unroll
      for (int i = 0; i < 32; i += 4) {
        a0 = dot2(w[i + 0], (uint)__builtin_amdgcn_readlane(h0, 32 + i + 0), a0);
        a1 = dot2(w[i + 1], (uint)__builtin_amdgcn_readlane(h0, 32 + i + 1), a1);
        a2 = dot2(w[i + 2], (uint)__builtin_amdgcn_readlane(h0, 32 + i + 2), a2);
        a3 = dot2(w[i + 3], (uint)__builtin_amdgcn_readlane(h0, 32 + i + 3), a3);
      }
    } else {
      // (1b) wave 7: LDS-flag spin (lgkm-only; NO vmem ops in this wave's poll path)
      if (step > 0) {
        while (__hip_atomic_load(&hflag[par], __ATOMIC_ACQUIRE,
                                 __HIP_MEMORY_SCOPE_WORKGROUP) != (uint)step) {}
        // (2b) matvec from uniform LDS broadcast reads of the relayed kq=3 block
        const uint4* hp4 = (const uint4*)&hrelay[par][0];
#pragma unroll
        for (int i4 = 0; i4 < 8; ++i4) {
          uint4 h4 = hp4[i4];          // wave-uniform -> broadcast, conflict-free
          a0 = dot2(w[4 * i4 + 0], h4.x, a0);
          a1 = dot2(w[4 * i4 + 1], h4.y, a1);
          a2 = dot2(w[4 * i4 + 2], h4.z, a2);
          a3 = dot2(w[4 * i4 + 3], h4.w, a3);
        }
      }
    }
    pl[step & 1][kq][rid] = (a0 + a1) + (a2 + a3);   // lanes stride-1: conflict-free

    __syncthreads();                   // the only barrier per step

    // (3) finale on wave 7, lanes 0..31: reduce + activations + publish + out
    if (v == 7 && l < 32) {
      const float (*pp)[128] = pl[step & 1];
      float s0 = (pp[0][l]      + pp[1][l])      + (pp[2][l]      + pp[3][l])      + x0;
      float s1 = (pp[0][32 + l] + pp[1][32 + l]) + (pp[2][32 + l] + pp[3][32 + l]) + x1;
      float s2 = (pp[0][64 + l] + pp[1][64 + l]) + (pp[2][64 + l] + pp[3][64 + l]) + x2;
      float s3 = (pp[0][96 + l] + pp[1][96 + l]) + (pp[2][96 + l] + pp[3][96 + l]) + x3;
      float iv = sigm(s0), fv = sigm(s1), gv = tanh_(s2), ov = sigm(s3);
      c = fv * c + iv * gv;
      float hval = ov * tanh_(c);
      float hA = __shfl(hval, 2 * (l & 15));
      float hB = __shfl(hval, 2 * (l & 15) + 1);
      if (l < 16) {                    // publish FIRST (critical path)
        f16x2 pk; pk.x = (f16)hA; pk.y = (f16)hB;
        uint pku = __builtin_bit_cast(uint, pk);
        u64 val = (u64)pku | ((u64)(uint)(step + 1) << 32);
        __hip_atomic_store(hb + (step & 1) * 128 + q * 16 + l, val,
                           __ATOMIC_RELAXED, __HIP_MEMORY_SCOPE_AGENT);
      }
      out[(step * BATCH + b) * HID + q * 32 + l] = hval;
      if (step + 1 < SEQ) {            // x-prefetch: ack retires under next spin
        ushort4 xv = *(const ushort4*)(proj + (long)ev[step + 1] * G4 + (q * 32 + l) * 4);
        x0 = f16u(xv.x); x1 = f16u(xv.y); x2 = f16u(xv.z); x3 = f16u(xv.w);
      }
    }
    // hazards: pl[s&1] reads (finale s) precede barrier(s+1); rewritten step s+2
    // after barrier(s+1). hrelay/hflag slot par reused at step s+2: wave 6 reaches
    // step s+2 only after barrier(s+1), which wave 7 passes only after its spin(s+1)
    // and finale(s) -- no overlap. hb slot reuse: R5-proven publish-order argument.
  }
}

extern "C" void kernel_launch(void* const* d_in, const int* in_sizes, int n_in,
                              void* d_out, int out_size, void* d_ws, size_t ws_size,
                              hipStream_t stream) {
  (void)n_in; (void)out_size; (void)ws_size;
  const int* evs = (const int*)d_in[0];
  const int* anc = (const int*)d_in[1];
  const float* weight = (const float*)d_in[2];
  const float* emb = (const float*)d_in[3];
  const float* wih = (const float*)d_in[4];
  const float* whh = (const float*)d_in[5];
  const float* bih = (const float*)d_in[6];
  const float* bhh = (const float*)d_in[7];
  int D = in_sizes[1] / N_TYPES;

  char* ws = (char*)d_ws;
  f16* path = (f16*)(ws);                       // 10000*256*2 = 5,120,000 (dead after k_gemm)
  f16* wih_h = (f16*)(ws + 5242880);            // 524,288
  uint* whh_t = (uint*)(ws + 5767168);          // 524,288
  float* bias = (float*)(ws + 6291456);         // 4,096
  f16* proj = (f16*)(ws + 6295552);             // 10000*1024*2 = 20,480,000 (gate-packed)
  u64* hglob = (u64*)(ws + 26775552);           // 32*2*128*8 = 65,536
  float* out = (float*)d_out;

  k_conv<<<1024, 256, 0, stream>>>(wih, whh, bih, bhh, wih_h, whh_t, bias);
  k_path<<<N_TYPES, 256, 0, stream>>>(anc, weight, emb, D, path);
  k_gemm<<<dim3(79, 8), 256, 0, stream>>>(path, wih_h, bias, proj);
  hipMemsetAsync(hglob, 0, 32 * 2 * 128 * 8, stream);   // zero tags (replay-safe)
  k_lstm<<<256, 512, 0, stream>>>(evs, proj, whh_t, hglob, out);
}